// Round 6
// baseline (307.521 us; speedup 1.0000x reference)
//
#include <hip/hip_runtime.h>
#include <hip/hip_bf16.h>

#define NN 100000
#define EE 400000
#define STRIPS 6250          // NN/16, exact
#define WPT 2048             // waves per type: 128 blocks * 16 waves

typedef unsigned short u16;
typedef __attribute__((ext_vector_type(4))) float floatx4;
typedef __attribute__((ext_vector_type(8))) short shortx8;
typedef __attribute__((ext_vector_type(4))) unsigned short ushortx4;
typedef __attribute__((ext_vector_type(8))) unsigned short ushortx8;

__device__ __forceinline__ u16 f2bf(float f) {
    unsigned u = __float_as_uint(f);
    u += 0x7FFFu + ((u >> 16) & 1u);
    return (u16)(u >> 16);
}

// ---- degree masks: idempotent byte stores, int4-vectorized edge reads
__global__ __launch_bounds__(256) void mark(
    const int4* __restrict__ daa, const int4* __restrict__ dab,
    const int4* __restrict__ dba, unsigned char* __restrict__ m) {
    int i = blockIdx.x * 256 + threadIdx.x;
    if (i < EE / 4) {
        int4 a = daa[i], b = dab[i], c = dba[i];
        m[a.x] = 1; m[a.y] = 1; m[a.z] = 1; m[a.w] = 1;
        m[NN + b.x] = 1; m[NN + b.y] = 1; m[NN + b.z] = 1; m[NN + b.w] = 1;
        m[2 * NN + c.x] = 1; m[2 * NN + c.y] = 1; m[2 * NN + c.z] = 1; m[2 * NN + c.w] = 1;
    }
}

// ---- persistent fused 2-layer. out = relu(s^2*(z@W1) + s*b1), z = relu(feat@W0+b0).
// Transposed MFMA form D = W^T x feat^T (layouts HW-verified R3-R5).
// R6: 1024-thr blocks, 128 KB LDS, 1 block/CU -> 16 waves/CU (R5 was 8, latency-
// starved at 2.2 TB/s). Static strip ownership, counted loop, UNCONDITIONAL
// wrapped VGPR prefetch of the next strip (branch-free software pipeline).
__global__ __launch_bounds__(1024, 1) void fused2(
    const float* __restrict__ featA, const float* __restrict__ featB,
    const float* __restrict__ Wr0, const float* __restrict__ Wr1,
    const float* __restrict__ br0, const float* __restrict__ br1,
    const unsigned char* __restrict__ masks, float* __restrict__ out) {
    __shared__ u16 lds[65536];   // [W0f 16K][W1f 16K][h1: 16 waves x 2048] = 128 KB

    const int type = blockIdx.x >> 7;           // 128 blocks per type
    const int bid = blockIdx.x & 127;
    const float* feat = type ? featB : featA;
    const float* W0 = Wr0 + type * 16384;
    const float* W1 = Wr1 + type * 16384;
    const float* b0 = br0 + type * 128;
    const float* b1 = br1 + type * 128;
    float* outp = out + (size_t)type * NN * 128;

    const int t = threadIdx.x;
    const int wave = t >> 6, lane = t & 63;
    const int quad = lane >> 4, mrow = lane & 15;
    const int gw = bid * 16 + wave;             // [0, WPT)
    const int niter = (STRIPS - gw + WPT - 1) / WPT;   // 3 or 4

    // ---- prefetch strip gw (issued BEFORE the staging barrier)
    int s = gw;
    floatx4 pf[8];
    unsigned char pm0, pm1 = 0;
    {
        const float* arow = feat + (size_t)(s * 16 + mrow) * 128;
#pragma unroll
        for (int ks = 0; ks < 4; ++ks) {
            pf[2 * ks]     = *(const floatx4*)(arow + ks * 32 + quad * 8);
            pf[2 * ks + 1] = *(const floatx4*)(arow + ks * 32 + quad * 8 + 4);
        }
        int row = s * 16 + mrow;
        if (type) pm0 = masks[NN + row];
        else { pm0 = masks[row]; pm1 = masks[2 * NN + row]; }
    }

    // ---- stage W0,W1 -> bf16 MFMA A-frag order (once per block)
#pragma unroll
    for (int i = 0; i < 4; ++i) {
        int g = i * 1024 + t;                   // [0, 4096) granules of 8
        int mat = g >> 11;
        int gg = g & 2047;
        int chunk = gg >> 6;                    // ks*8 + nt
        int l2 = gg & 63;
        int kbase = (chunk >> 3) * 32 + (l2 >> 4) * 8;
        int n = (chunk & 7) * 16 + (l2 & 15);
        const float* W = mat ? W1 : W0;
        ushortx8 p;
#pragma unroll
        for (int j = 0; j < 8; ++j) p[j] = f2bf(W[(kbase + j) * 128 + n]);
        *(ushortx8*)&lds[mat * 16384 + chunk * 512 + l2 * 8] = p;
    }
    __syncthreads();   // the only barrier

    const int h1base = 32768 + wave * 2048;

    for (int it = 0; it < niter; ++it) {
        // consume prefetch: bf16 B-frags + scale
        shortx8 bfrag[4];
#pragma unroll
        for (int ks = 0; ks < 4; ++ks) {
            floatx4 f0 = pf[2 * ks], f1 = pf[2 * ks + 1];
            union { shortx8 v; u16 u[8]; } uu;
            uu.u[0] = f2bf(f0[0]); uu.u[1] = f2bf(f0[1]);
            uu.u[2] = f2bf(f0[2]); uu.u[3] = f2bf(f0[3]);
            uu.u[4] = f2bf(f1[0]); uu.u[5] = f2bf(f1[1]);
            uu.u[6] = f2bf(f1[2]); uu.u[7] = f2bf(f1[3]);
            bfrag[ks] = uu.v;
        }
        const float scl = type ? (1.0f + (float)pm0) * 0.5f
                               : (1.0f + (float)pm0 + (float)pm1) * (1.0f / 3.0f);
        const float s2 = scl * scl;
        const int row = s * 16 + mrow;

        // unconditional wrapped prefetch of next strip (hidden under GEMMs;
        // last iteration's prefetch is discarded — always a valid address)
        int sn = s + WPT;
        if (sn >= STRIPS) sn -= STRIPS;
        {
            const float* arow = feat + (size_t)(sn * 16 + mrow) * 128;
#pragma unroll
            for (int ks = 0; ks < 4; ++ks) {
                pf[2 * ks]     = *(const floatx4*)(arow + ks * 32 + quad * 8);
                pf[2 * ks + 1] = *(const floatx4*)(arow + ks * 32 + quad * 8 + 4);
            }
            int nrow = sn * 16 + mrow;
            if (type) pm0 = masks[NN + nrow];
            else { pm0 = masks[nrow]; pm1 = masks[2 * NN + nrow]; }
        }

        // GEMM1: acc[nt] = W0^T tile(nt) x feat^T
        floatx4 acc[8];
#pragma unroll
        for (int nt = 0; nt < 8; ++nt) acc[nt] = (floatx4){0.f, 0.f, 0.f, 0.f};
#pragma unroll
        for (int ks = 0; ks < 4; ++ks)
#pragma unroll
            for (int nt = 0; nt < 8; ++nt) {
                shortx8 af = *(const shortx8*)&lds[((ks * 8 + nt) << 9) + lane * 8];
                acc[nt] = __builtin_amdgcn_mfma_f32_16x16x32_bf16(af, bfrag[ks], acc[nt], 0, 0, 0);
            }

        // epilogue1: z = relu(acc + b0), wave-private h1 in GEMM2 B-frag order
#pragma unroll
        for (int nt = 0; nt < 8; ++nt) {
            floatx4 bv = *(const floatx4*)(b0 + nt * 16 + quad * 4);
            ushortx4 p;
#pragma unroll
            for (int r = 0; r < 4; ++r)
                p[r] = f2bf(fmaxf(acc[nt][r] + bv[r], 0.0f));
            int q2 = (2 * nt + (quad >> 1)) & 3;
            *(ushortx4*)&lds[h1base + (nt >> 1) * 512 + q2 * 128 + mrow * 8 + (quad & 1) * 4] = p;
        }

        shortx8 h1b[4];
#pragma unroll
        for (int ks = 0; ks < 4; ++ks)
            h1b[ks] = *(const shortx8*)&lds[h1base + ks * 512 + lane * 8];

        // GEMM2: acc2[nt] = W1^T tile(nt) x z^T
        floatx4 acc2[8];
#pragma unroll
        for (int nt = 0; nt < 8; ++nt) acc2[nt] = (floatx4){0.f, 0.f, 0.f, 0.f};
#pragma unroll
        for (int ks = 0; ks < 4; ++ks)
#pragma unroll
            for (int nt = 0; nt < 8; ++nt) {
                shortx8 af = *(const shortx8*)&lds[16384 + ((ks * 8 + nt) << 9) + lane * 8];
                acc2[nt] = __builtin_amdgcn_mfma_f32_16x16x32_bf16(af, h1b[ks], acc2[nt], 0, 0, 0);
            }

        // epilogue2: out = relu(s^2*acc2 + s*b1), 8 x float4 per lane
        float* orow = outp + (size_t)row * 128;
#pragma unroll
        for (int nt = 0; nt < 8; ++nt) {
            floatx4 bv = *(const floatx4*)(b1 + nt * 16 + quad * 4);
            floatx4 o;
#pragma unroll
            for (int r = 0; r < 4; ++r)
                o[r] = fmaxf(s2 * acc2[nt][r] + scl * bv[r], 0.0f);
            *(floatx4*)(orow + nt * 16 + quad * 4) = o;
        }

        s = sn;
    }
}

extern "C" void kernel_launch(void* const* d_in, const int* in_sizes, int n_in,
                              void* d_out, int out_size, void* d_ws, size_t ws_size,
                              hipStream_t stream) {
    (void)in_sizes; (void)n_in; (void)out_size; (void)ws_size;
    const float* featA = (const float*)d_in[0];
    const float* featB = (const float*)d_in[1];
    const int* dst_aa = (const int*)d_in[3];
    const int* dst_ab = (const int*)d_in[5];
    const int* dst_ba = (const int*)d_in[7];
    const float* Wr0 = (const float*)d_in[10];
    const float* br0 = (const float*)d_in[11];
    const float* Wr1 = (const float*)d_in[16];
    const float* br1 = (const float*)d_in[17];

    unsigned char* masks = (unsigned char*)d_ws;    // 3*NN bytes

    hipMemsetAsync(masks, 0, (size_t)3 * NN, stream);
    mark<<<(EE / 4 + 255) / 256, 256, 0, stream>>>(
        (const int4*)dst_aa, (const int4*)dst_ab, (const int4*)dst_ba, masks);
    fused2<<<256, 1024, 0, stream>>>(featA, featB, Wr0, Wr1, br0, br1,
                                     masks, (float*)d_out);
}

// Round 7
// 241.678 us; speedup vs baseline: 1.2724x; 1.2724x over previous
//
#include <hip/hip_runtime.h>
#include <hip/hip_bf16.h>

#define NN 100000
#define EE 400000
#define STRIPS 6250          // NN/16 per type, exact
#define WPT 2048             // waves per type: 256 blocks * 8 waves

typedef unsigned short u16;
typedef unsigned int u32;
typedef __attribute__((ext_vector_type(4))) float floatx4;
typedef __attribute__((ext_vector_type(8))) short shortx8;
typedef __attribute__((ext_vector_type(8))) unsigned short ushortx8;

__device__ __forceinline__ u16 f2bf(float f) {
    unsigned u = __float_as_uint(f);
    u += 0x7FFFu + ((u >> 16) & 1u);
    return (u16)(u >> 16);
}

// ---- degree masks: idempotent byte stores, int4-vectorized edge reads
__global__ __launch_bounds__(256) void mark(
    const int4* __restrict__ daa, const int4* __restrict__ dab,
    const int4* __restrict__ dba, unsigned char* __restrict__ m) {
    int i = blockIdx.x * 256 + threadIdx.x;
    if (i < EE / 4) {
        int4 a = daa[i], b = dab[i], c = dba[i];
        m[a.x] = 1; m[a.y] = 1; m[a.z] = 1; m[a.w] = 1;
        m[NN + b.x] = 1; m[NN + b.y] = 1; m[NN + b.z] = 1; m[NN + b.w] = 1;
        m[2 * NN + c.x] = 1; m[2 * NN + c.y] = 1; m[2 * NN + c.z] = 1; m[2 * NN + c.w] = 1;
    }
}

// ---- Wtf: W -> bf16 in MFMA A-frag order (once, globally; blocks re-read via L3).
// Wtf[mat][chunk=ks*8+nt][lane][j] = W[mat][k][n], k=ks*32+(lane>>4)*8+j, n=(chunk&7)*16+(lane&15)
__global__ __launch_bounds__(256) void conv_wt(
    const float* __restrict__ Wr0, const float* __restrict__ Wr1, u16* __restrict__ Wtf) {
    int idx = blockIdx.x * 256 + threadIdx.x;   // 4*16384 exact
    int mat = idx >> 14;
    int fidx = idx & 16383;
    int chunk = fidx >> 9;
    int lane = (fidx >> 3) & 63;
    int j = fidx & 7;
    int k = (chunk >> 3) * 32 + ((lane >> 4) & 3) * 8 + j;
    int n = (chunk & 7) * 16 + (lane & 15);
    const float* W = (mat < 2) ? (Wr0 + mat * 16384) : (Wr1 + (mat - 2) * 16384);
    Wtf[idx] = f2bf(W[k * 128 + n]);
}

// ---- persistent fused 2-layer. out = relu(s^2*(z@W1) + s*b1), z = relu(feat@W0+b0).
// Transposed MFMA form D = W^T x feat^T (layouts HW-verified R3-R6).
// R7 shell: 512 blocks x 512 thr (8 waves), 96 KB LDS -> 1 block/CU, 8 waves/CU
// (2 waves/SIMD -> 256-VGPR budget, NO spill; R6's 4 waves/SIMD spilled).
// W staged from precomputed bf16 frag-order Wtf with coalesced 16B copies
// (R5/R6 staged via 128 scattered scalar fp32 loads/thread — removed).
__global__ __launch_bounds__(512, 2) void fused2(
    const float* __restrict__ featA, const float* __restrict__ featB,
    const u16* __restrict__ Wtf,
    const float* __restrict__ br0, const float* __restrict__ br1,
    const unsigned char* __restrict__ masks, float* __restrict__ out) {
    __shared__ u16 lds[49152];   // [W0f 16384][W1f 16384][h1: 8 waves x 2048] = 96 KB

    const int type = blockIdx.x >> 8;           // 256 blocks per type
    const int bid = blockIdx.x & 255;
    const float* feat = type ? featB : featA;
    const u16* W0g = Wtf + type * 16384;
    const u16* W1g = Wtf + (2 + type) * 16384;
    const float* b0 = br0 + type * 128;
    const float* b1 = br1 + type * 128;
    float* outp = out + (size_t)type * NN * 128;

    const int t = threadIdx.x;
    const int wave = t >> 6, lane = t & 63;
    const int quad = lane >> 4, mrow = lane & 15;
    const int gw = bid * 8 + wave;              // [0, WPT)
    const int niter = (STRIPS - gw + WPT - 1) / WPT;   // 3 or 4

    // ---- prefetch strip gw (issued BEFORE the staging barrier)
    int s = gw;
    floatx4 pf[8];
    unsigned char pm0, pm1 = 0;
    {
        const float* arow = feat + (size_t)(s * 16 + mrow) * 128;
#pragma unroll
        for (int ks = 0; ks < 4; ++ks) {
            pf[2 * ks]     = *(const floatx4*)(arow + ks * 32 + quad * 8);
            pf[2 * ks + 1] = *(const floatx4*)(arow + ks * 32 + quad * 8 + 4);
        }
        int row = s * 16 + mrow;
        if (type) pm0 = masks[NN + row];
        else { pm0 = masks[row]; pm1 = masks[2 * NN + row]; }
    }

    // ---- stage W0f,W1f: linear coalesced 16B copies (L3-hot Wtf)
#pragma unroll
    for (int i = 0; i < 4; ++i) {
        int off = (i * 512 + t) * 8;            // [0, 16384)
        *(ushortx8*)&lds[off]         = *(const ushortx8*)&W0g[off];
        *(ushortx8*)&lds[16384 + off] = *(const ushortx8*)&W1g[off];
    }
    __syncthreads();   // the only barrier

    const int h1base = 32768 + wave * 2048;

    for (int it = 0; it < niter; ++it) {
        // consume prefetch: packed bf16 B-frags + scale
        shortx8 bfrag[4];
#pragma unroll
        for (int ks = 0; ks < 4; ++ks) {
            floatx4 f0 = pf[2 * ks], f1 = pf[2 * ks + 1];
            union { shortx8 v; __hip_bfloat162 h[4]; } uu;
            uu.h[0] = __float22bfloat162_rn(make_float2(f0[0], f0[1]));
            uu.h[1] = __float22bfloat162_rn(make_float2(f0[2], f0[3]));
            uu.h[2] = __float22bfloat162_rn(make_float2(f1[0], f1[1]));
            uu.h[3] = __float22bfloat162_rn(make_float2(f1[2], f1[3]));
            bfrag[ks] = uu.v;
        }
        const float scl = type ? (1.0f + (float)pm0) * 0.5f
                               : (1.0f + (float)pm0 + (float)pm1) * (1.0f / 3.0f);
        const float s2 = scl * scl;
        const int row = s * 16 + mrow;

        // prefetch next strip (wave-uniform condition; hidden under both GEMMs)
        const int sn = s + WPT;
        if (it + 1 < niter) {
            const float* arow = feat + (size_t)(sn * 16 + mrow) * 128;
#pragma unroll
            for (int ks = 0; ks < 4; ++ks) {
                pf[2 * ks]     = *(const floatx4*)(arow + ks * 32 + quad * 8);
                pf[2 * ks + 1] = *(const floatx4*)(arow + ks * 32 + quad * 8 + 4);
            }
            int nrow = sn * 16 + mrow;
            if (type) pm0 = masks[NN + nrow];
            else { pm0 = masks[nrow]; pm1 = masks[2 * NN + nrow]; }
        }

        // GEMM1: acc[nt] = W0^T tile(nt) x feat^T
        floatx4 acc[8];
#pragma unroll
        for (int nt = 0; nt < 8; ++nt) acc[nt] = (floatx4){0.f, 0.f, 0.f, 0.f};
#pragma unroll
        for (int ks = 0; ks < 4; ++ks)
#pragma unroll
            for (int nt = 0; nt < 8; ++nt) {
                shortx8 af = *(const shortx8*)&lds[((ks * 8 + nt) << 9) + lane * 8];
                acc[nt] = __builtin_amdgcn_mfma_f32_16x16x32_bf16(af, bfrag[ks], acc[nt], 0, 0, 0);
            }

        // epilogue1: z = relu(acc + b0), wave-private h1 in GEMM2 B-frag order
#pragma unroll
        for (int nt = 0; nt < 8; ++nt) {
            floatx4 bv = *(const floatx4*)(b0 + nt * 16 + quad * 4);
            union { u32 w[2]; unsigned long long d; } p;
            __hip_bfloat162 z01 = __float22bfloat162_rn(make_float2(
                fmaxf(acc[nt][0] + bv[0], 0.0f), fmaxf(acc[nt][1] + bv[1], 0.0f)));
            __hip_bfloat162 z23 = __float22bfloat162_rn(make_float2(
                fmaxf(acc[nt][2] + bv[2], 0.0f), fmaxf(acc[nt][3] + bv[3], 0.0f)));
            p.w[0] = *(u32*)&z01; p.w[1] = *(u32*)&z23;
            int q2 = (2 * nt + (quad >> 1)) & 3;
            *(unsigned long long*)&lds[h1base + (nt >> 1) * 512 + q2 * 128 + mrow * 8 + (quad & 1) * 4] = p.d;
        }

        shortx8 h1b[4];
#pragma unroll
        for (int ks = 0; ks < 4; ++ks)
            h1b[ks] = *(const shortx8*)&lds[h1base + ks * 512 + lane * 8];

        // GEMM2: acc2[nt] = W1^T tile(nt) x z^T
        floatx4 acc2[8];
#pragma unroll
        for (int nt = 0; nt < 8; ++nt) acc2[nt] = (floatx4){0.f, 0.f, 0.f, 0.f};
#pragma unroll
        for (int ks = 0; ks < 4; ++ks)
#pragma unroll
            for (int nt = 0; nt < 8; ++nt) {
                shortx8 af = *(const shortx8*)&lds[16384 + ((ks * 8 + nt) << 9) + lane * 8];
                acc2[nt] = __builtin_amdgcn_mfma_f32_16x16x32_bf16(af, h1b[ks], acc2[nt], 0, 0, 0);
            }

        // epilogue2: out = relu(s^2*acc2 + s*b1), 8 x float4 per lane
        float* orow = outp + (size_t)row * 128;
#pragma unroll
        for (int nt = 0; nt < 8; ++nt) {
            floatx4 bv = *(const floatx4*)(b1 + nt * 16 + quad * 4);
            floatx4 o;
#pragma unroll
            for (int r = 0; r < 4; ++r)
                o[r] = fmaxf(s2 * acc2[nt][r] + scl * bv[r], 0.0f);
            *(floatx4*)(orow + nt * 16 + quad * 4) = o;
        }

        s = sn;
    }
}

extern "C" void kernel_launch(void* const* d_in, const int* in_sizes, int n_in,
                              void* d_out, int out_size, void* d_ws, size_t ws_size,
                              hipStream_t stream) {
    (void)in_sizes; (void)n_in; (void)out_size; (void)ws_size;
    const float* featA = (const float*)d_in[0];
    const float* featB = (const float*)d_in[1];
    const int* dst_aa = (const int*)d_in[3];
    const int* dst_ab = (const int*)d_in[5];
    const int* dst_ba = (const int*)d_in[7];
    const float* Wr0 = (const float*)d_in[10];
    const float* br0 = (const float*)d_in[11];
    const float* Wr1 = (const float*)d_in[16];
    const float* br1 = (const float*)d_in[17];

    char* ws = (char*)d_ws;
    u16* Wtf = (u16*)ws;                            // 128 KB
    unsigned char* masks = (unsigned char*)(ws + 131072);   // 3*NN bytes

    hipMemsetAsync(masks, 0, (size_t)3 * NN, stream);
    mark<<<(EE / 4 + 255) / 256, 256, 0, stream>>>(
        (const int4*)dst_aa, (const int4*)dst_ab, (const int4*)dst_ba, masks);
    conv_wt<<<256, 256, 0, stream>>>(Wr0, Wr1, Wtf);
    fused2<<<512, 512, 0, stream>>>(featA, featB, Wtf, br0, br1, masks, (float*)d_out);
}